// Round 4
// baseline (241.853 us; speedup 1.0000x reference)
//
#include <hip/hip_runtime.h>

// Problem: z [B=16, D=128, T=4096] fp32, codebook [K=1024, D=128] fp32.
// out [B, D, T] fp32 = codebook[argmin_k ||z_token - c_k||^2] scattered back.
// Stage 1: argmin d^2 == argmax s, s = z.c - 0.5|c|^2 (per-token |z|^2 constant),
//          computed in bf16 MFMA with packed (score|idx) argmax + top-2 margin.
// Tokens with margin < DELTA (~5.5 sigma of the bf16 error model) are re-scored
// EXACTLY (fp64) by vq_rescue: d2 = |z|^2 - 2 z.c + |c|^2, first-index tiebreak.
// Desk-audited r3: fragment-permutation invariance, barrier chains, top-2 merge,
// negative-score tiebreak direction, list capacity == 65536 (overflow-impossible).

#define Dd 128
#define Tt 4096
#define Kc 1024
#define DT (Dd*Tt)
#define DELTA 0.3f
#define NEG_INF (-__builtin_inff())

typedef float  floatx4 __attribute__((ext_vector_type(4)));
typedef short  shortx8 __attribute__((ext_vector_type(8)));

__device__ __forceinline__ unsigned f2bf(float f) {
  unsigned u = __float_as_uint(f);
  u = u + 0x7fffu + ((u >> 16) & 1u);   // RNE to bf16
  return u >> 16;
}

#define ASYNC_COPY16(dst, src) \
  __builtin_amdgcn_global_load_lds((const __attribute__((address_space(1))) void*)(src), \
                                   (__attribute__((address_space(3))) void*)(dst), 16, 0, 0)

// ---------------- prep: codebook fp32 -> bf16 + fp32 bias + fp64 |c|^2 ----------------
__global__ __launch_bounds__(256) void vq_prep(const float* __restrict__ cb,
                                               unsigned short* __restrict__ cbbf,
                                               float* __restrict__ bias,
                                               double* __restrict__ cc64) {
  int c = blockIdx.x * 256 + threadIdx.x;
  if (c >= Kc) return;
  const float4* row = (const float4*)(cb + (size_t)c * Dd);
  uint2* dst = (uint2*)(cbbf + (size_t)c * Dd);
  double s = 0.0;
  #pragma unroll 8
  for (int q = 0; q < 32; q++) {
    float4 v = row[q];
    s = fma((double)v.x, (double)v.x, s);
    s = fma((double)v.y, (double)v.y, s);
    s = fma((double)v.z, (double)v.z, s);
    s = fma((double)v.w, (double)v.w, s);
    uint2 p;
    p.x = f2bf(v.x) | (f2bf(v.y) << 16);
    p.y = f2bf(v.z) | (f2bf(v.w) << 16);
    dst[q] = p;
  }
  cc64[c] = s;                       // exact-ish |c|^2 for the fp64 rescue
  bias[c] = (float)(-0.5 * s);       // MFMA C-init for stage 1
}

// ---------------- stage 1: fused bf16 MFMA scores + packed argmax + margin ----------------
// Grid: 512 WGs x 256 thr. WG = 128 consecutive tokens; loops all 1024 codes in 8 chunks of 128.
// MFMA 16x16x32: M = codes (A from codebook), N = tokens (B from z), K = dims.
// A-frag: lane holds 8 k-contig elems, row = lane&15, k0 = (lane>>4)*8.  B symmetric.
// (Any k-permutation of this mapping is harmless: A and B share it; dot is perm-invariant.)
// C/D: col(n) = lane&15, row(m) = (lane>>4)*4 + reg  [m89].
__global__ __launch_bounds__(256, 2) void vq_stage1(const float* __restrict__ z,
                                                    const float* __restrict__ cb,
                                                    const unsigned short* __restrict__ cbbf,
                                                    const float* __restrict__ bias,
                                                    unsigned* __restrict__ counter,
                                                    unsigned* __restrict__ list,
                                                    float* __restrict__ out) {
  __shared__ uint4 cb_lds4[2048];            // 32 KB  [code 128][k 128] bf16, XOR-swizzled
  __shared__ uint4 z_lds4[2048];             // 32 KB  [token 128][k 128] bf16, XOR-swizzled
  __shared__ float2 res[128][8];             // 8 KB   per-token (M1packed, M2) x 8 slots
  __shared__ unsigned idxlds[128];
  char* cb_lds = (char*)cb_lds4;
  char* z_lds  = (char*)z_lds4;

  const int tid  = threadIdx.x;
  const int lane = tid & 63;
  const int wid  = tid >> 6;       // 0..3
  const int wm   = wid & 1;        // code half
  const int wn   = wid >> 1;       // token half
  const int lrow = lane >> 4;      // 0..3
  const int lcol = lane & 15;

  const int token0 = blockIdx.x * 128;       // flat token base
  const int b  = token0 >> 12;               // /4096
  const int t0 = token0 & 4095;

  // ---- stage z tile: [token][k] bf16, swizzled byte = (token*256 + d*2) ^ ((token&7)<<4)
  // Loads are wave-coalesced along tokens (lane i -> consecutive address), 4B/lane.
  {
    const int token = tid & 127;
    const int dh = tid >> 7;
    const float* zb = z + (size_t)b * DT + (size_t)(t0 + token);
    #pragma unroll 4
    for (int i = 0; i < 32; i++) {
      int d = (i * 2 + dh) * 2;                       // even d
      float f0 = zb[(size_t)d * Tt];
      float f1 = zb[(size_t)(d + 1) * Tt];
      unsigned u = f2bf(f0) | (f2bf(f1) << 16);
      unsigned off = ((unsigned)(token * 256 + d * 2)) ^ (((unsigned)(token & 7)) << 4);
      *(unsigned*)(z_lds + off) = u;
    }
  }

  float M1[4], M2[4];
  #pragma unroll
  for (int nf = 0; nf < 4; nf++) { M1[nf] = NEG_INF; M2[nf] = NEG_INF; }

  #pragma unroll 1
  for (int cc = 0; cc < 8; cc++) {
    const int ccbase = cc * 128;
    __syncthreads();  // previous chunk's reads done before overwrite
    // stage codebook chunk: linear LDS dest, pre-swizzled global source (m173 pattern)
    #pragma unroll
    for (int i = 0; i < 8; i++) {
      unsigned db  = (unsigned)(i * 4096 + wid * 1024 + lane * 16);
      unsigned row = db >> 8;
      unsigned kb  = db & 255u;
      const char* src = (const char*)cbbf + (((unsigned)ccbase + row) << 8) + (kb ^ ((row & 7u) << 4));
      char* dst = cb_lds + i * 4096 + wid * 1024;    // wave-uniform base; HW adds lane*16
      ASYNC_COPY16(dst, src);
    }
    // bias -> accumulator init (C-input of MFMA): reg j holds code row lrow*4+j
    floatx4 acc[4][4];
    #pragma unroll
    for (int mf = 0; mf < 4; mf++) {
      floatx4 bv = *(const floatx4*)(bias + ccbase + wm * 64 + mf * 16 + lrow * 4);
      #pragma unroll
      for (int nf = 0; nf < 4; nf++) acc[mf][nf] = bv;
    }
    __syncthreads();  // staging complete (compiler drains vmcnt before barrier)

    #pragma unroll
    for (int ks = 0; ks < 4; ks++) {
      shortx8 af[4], bfr[4];
      const int kbyte = (ks * 32 + lrow * 8) * 2;
      #pragma unroll
      for (int mf = 0; mf < 4; mf++) {
        int row = wm * 64 + mf * 16 + lcol;
        af[mf] = *(const shortx8*)(cb_lds + (((unsigned)(row * 256 + kbyte)) ^ (((unsigned)(row & 7)) << 4)));
      }
      #pragma unroll
      for (int nf = 0; nf < 4; nf++) {
        int row = wn * 64 + nf * 16 + lcol;
        bfr[nf] = *(const shortx8*)(z_lds + (((unsigned)(row * 256 + kbyte)) ^ (((unsigned)(row & 7)) << 4)));
      }
      #pragma unroll
      for (int mf = 0; mf < 4; mf++)
        #pragma unroll
        for (int nf = 0; nf < 4; nf++)
          acc[mf][nf] = __builtin_amdgcn_mfma_f32_16x16x32_bf16(af[mf], bfr[nf], acc[mf][nf], 0, 0, 0);
    }

    // epilogue: packed argmax + second-best. pack = clear 10 LSBs, OR in code idx.
    // Packing perturbs margins by <= ~0.016 (|s|<128) -- absorbed in DELTA.
    // Negative scores: OR'd idx makes value MORE negative -> fmaxf prefers smaller
    // idx on cleared-mantissa ties (matches reference first-index); ties are
    // rescued anyway (margin ~ 0 < DELTA).
    #pragma unroll
    for (int mf = 0; mf < 4; mf++) {
      const unsigned ib = (unsigned)(ccbase + wm * 64 + mf * 16 + lrow * 4);
      #pragma unroll
      for (int j = 0; j < 4; j++) {
        const unsigned idx = ib + j;
        #pragma unroll
        for (int nf = 0; nf < 4; nf++) {
          float s  = acc[mf][nf][j];
          float pf = __uint_as_float((__float_as_uint(s) & 0xFFFFFC00u) | idx);
          float tm = fminf(pf, M1[nf]);
          M2[nf] = fmaxf(M2[nf], tm);
          M1[nf] = fmaxf(M1[nf], pf);
        }
      }
    }
  }

  // combine 8 slots per token (standard top-2 merge; g2 exact global 2nd-best)
  #pragma unroll
  for (int nf = 0; nf < 4; nf++) {
    int token = wn * 64 + nf * 16 + lcol;
    res[token][wm * 4 + lrow] = make_float2(M1[nf], M2[nf]);
  }
  __syncthreads();

  if (tid < 128) {
    float g1 = NEG_INF, g2 = NEG_INF;
    #pragma unroll
    for (int s = 0; s < 8; s++) {
      float2 v = res[tid][s];
      float tm = fminf(v.x, g1);
      g1 = fmaxf(g1, v.x);
      g2 = fmaxf(g2, tm);
      g2 = fmaxf(g2, v.y);
    }
    unsigned idx = __float_as_uint(g1) & 1023u;
    idxlds[tid] = idx;
    if (g1 - g2 < DELTA) {
      unsigned pos = atomicAdd(counter, 1u);   // <= 65536 total, list capacity 65536
      list[pos] = (unsigned)(token0 + tid);
    }
  }
  __syncthreads();

  // gather + scatter-write candidate rows (flagged tokens get overwritten by rescue)
  {
    const int token = tid & 127;
    const int half  = tid >> 7;
    const unsigned idx = idxlds[token];
    const float4* crow = (const float4*)(cb + (size_t)idx * Dd);
    const size_t obase = (size_t)b * DT + (size_t)(t0 + token);
    #pragma unroll
    for (int q = 0; q < 16; q++) {
      int d = half * 64 + q * 4;
      float4 v = crow[d >> 2];
      out[obase + (size_t)(d + 0) * Tt] = v.x;
      out[obase + (size_t)(d + 1) * Tt] = v.y;
      out[obase + (size_t)(d + 2) * Tt] = v.z;
      out[obase + (size_t)(d + 3) * Tt] = v.w;
    }
  }
}

// ---------------- rescue: EXACT fp64 re-scan for flagged tokens ----------------
// d2 = |z|^2 - 2 z.c + |c|^2 in double (products of fp32 are exact in fp64);
// argmin with first-index tiebreak == true ranking of the reference formula.
// fp64 sits at the center of the reference's own fp32 rounding distribution,
// minimizing expected near-tie disagreement (no fp32 variant can do better).
__global__ __launch_bounds__(256) void vq_rescue(const float* __restrict__ z,
                                                 const float* __restrict__ cb,
                                                 const double* __restrict__ cc64,
                                                 const unsigned* __restrict__ counter,
                                                 const unsigned* __restrict__ list,
                                                 float* __restrict__ out) {
  const int tid = threadIdx.x;
  const unsigned count = *counter;
  __shared__ float zbuf[8][128];
  __shared__ double zz[8];
  __shared__ double rv[4][8];
  __shared__ int    rc[4][8];
  __shared__ int    fidx[8];
  __shared__ unsigned toks[8];

  for (unsigned base = blockIdx.x * 8u; base < count; base += gridDim.x * 8u) {
    unsigned rem = count - base;
    int nt = rem < 8u ? (int)rem : 8;
    __syncthreads();
    if (tid < nt) toks[tid] = list[base + tid];
    __syncthreads();
    for (int e = tid; e < nt * 128; e += 256) {
      int j = e >> 7, d = e & 127;
      unsigned tk = toks[j];
      zbuf[j][d] = z[(size_t)(tk >> 12) * DT + (size_t)d * Tt + (tk & 4095u)];
    }
    __syncthreads();
    if (tid < 8) {                         // |z|^2 per token in fp64
      double s = 0.0;
      #pragma unroll 16
      for (int d = 0; d < 128; d++) {
        double v = (double)zbuf[tid][d];
        s = fma(v, v, s);
      }
      zz[tid] = s;
    }

    double acc[8][4];
    #pragma unroll
    for (int j = 0; j < 8; j++)
      #pragma unroll
      for (int q = 0; q < 4; q++) acc[j][q] = 0.0;

    for (int d0 = 0; d0 < 128; d0 += 4) {
      double cvd[4][4];
      #pragma unroll
      for (int q = 0; q < 4; q++) {
        float4 cv = *(const float4*)(cb + (size_t)(q * 256 + tid) * Dd + d0);
        cvd[q][0] = (double)cv.x; cvd[q][1] = (double)cv.y;
        cvd[q][2] = (double)cv.z; cvd[q][3] = (double)cv.w;
      }
      #pragma unroll
      for (int j = 0; j < 8; j++) {
        float4 zv = *(const float4*)&zbuf[j][d0];
        double z0 = (double)zv.x, z1 = (double)zv.y, z2 = (double)zv.z, z3 = (double)zv.w;
        #pragma unroll
        for (int q = 0; q < 4; q++)
          acc[j][q] = fma(z0, cvd[q][0], fma(z1, cvd[q][1], fma(z2, cvd[q][2], fma(z3, cvd[q][3], acc[j][q]))));
      }
    }
    __syncthreads();   // zz ready

    #pragma unroll
    for (int j = 0; j < 8; j++) {
      double bv = __builtin_inf(); int bc = 0x7fffffff;
      double zzj = zz[j];
      #pragma unroll
      for (int q = 0; q < 4; q++) {
        int c = q * 256 + tid;
        double d2 = zzj - 2.0 * acc[j][q] + cc64[c];
        if (d2 < bv || (d2 == bv && c < bc)) { bv = d2; bc = c; }
      }
      #pragma unroll
      for (int off = 32; off > 0; off >>= 1) {
        double ov = __shfl_xor(bv, off);
        int    oc = __shfl_xor(bc, off);
        if (ov < bv || (ov == bv && oc < bc)) { bv = ov; bc = oc; }
      }
      if ((tid & 63) == 0) { rv[tid >> 6][j] = bv; rc[tid >> 6][j] = bc; }
    }
    __syncthreads();
    if (tid < 8) {
      int j = tid; double bv = rv[0][j]; int bc = rc[0][j];
      #pragma unroll
      for (int w = 1; w < 4; w++) {
        double ov = rv[w][j]; int oc = rc[w][j];
        if (ov < bv || (ov == bv && oc < bc)) { bv = ov; bc = oc; }
      }
      fidx[j] = bc;
    }
    __syncthreads();
    for (int j = 0; j < nt; j++) {
      unsigned tk = toks[j];
      int c = fidx[j];
      for (int d = tid; d < 128; d += 256)
        out[(size_t)(tk >> 12) * DT + (size_t)d * Tt + (tk & 4095u)] = cb[(size_t)c * Dd + d];
    }
  }
}

extern "C" void kernel_launch(void* const* d_in, const int* in_sizes, int n_in,
                              void* d_out, int out_size, void* d_ws, size_t ws_size,
                              hipStream_t stream) {
  const float* z  = (const float*)d_in[0];
  const float* cb = (const float*)d_in[1];
  float* out = (float*)d_out;

  // ws layout (544 KB total):
  //   counter u32 @0 | bias f32[1024] @4K | cc64 f64[1024] @16K |
  //   cbbf bf16[1024*128] @32K (256KB) | list u32[65536] @288K (256KB, overflow-proof)
  char* ws = (char*)d_ws;
  unsigned*       counter = (unsigned*)ws;
  float*          bias    = (float*)(ws + (4u << 10));
  double*         cc64    = (double*)(ws + (16u << 10));
  unsigned short* cbbf    = (unsigned short*)(ws + (32u << 10));
  unsigned*       list    = (unsigned*)(ws + (288u << 10));

  hipMemsetAsync(d_ws, 0, 4, stream);
  hipLaunchKernelGGL(vq_prep,   dim3(4),   dim3(256), 0, stream, cb, cbbf, bias, cc64);
  hipLaunchKernelGGL(vq_stage1, dim3(512), dim3(256), 0, stream, z, cb, cbbf, bias, counter, list, out);
  hipLaunchKernelGGL(vq_rescue, dim3(512), dim3(256), 0, stream, z, cb, cc64, counter, list, out);
}

// Round 5
// 208.662 us; speedup vs baseline: 1.1591x; 1.1591x over previous
//
#include <hip/hip_runtime.h>

// z [B=16, D=128, T=4096] fp32, codebook [K=1024, D=128] fp32.
// out = codebook[argmin_k ||z_tok - c_k||^2] scattered back to [B, D, T].
// Stage 1: argmax s, s = z.c - 0.5|c|^2, with z.c computed by bf16-SPLIT MFMA:
//   z = zh + zl, c = ch + cl (bf16 hi + bf16 residual);
//   s ~= zh.ch + zh.cl + zl.ch  (error sigma ~1e-4, bound ~5e-4)
// Unpacked (score,idx) top-2 per token; margin < DELTA=0.005 (>=10x bound) -> fp64 rescue.

#define Dd 128
#define Tt 4096
#define Kc 1024
#define DT (Dd*Tt)
#define DELTA 0.005f
#define NEG_INF (-__builtin_inff())

typedef float  floatx4 __attribute__((ext_vector_type(4)));
typedef short  shortx8 __attribute__((ext_vector_type(8)));

__device__ __forceinline__ unsigned f2bf(float f) {
  unsigned u = __float_as_uint(f);
  u = u + 0x7fffu + ((u >> 16) & 1u);   // RNE to bf16
  return u >> 16;
}
__device__ __forceinline__ float bf2f(unsigned h) { return __uint_as_float(h << 16); }

#define ASYNC_COPY16(dst, src) \
  __builtin_amdgcn_global_load_lds((const __attribute__((address_space(1))) void*)(src), \
                                   (__attribute__((address_space(3))) void*)(dst), 16, 0, 0)

// ---------------- prep: codebook -> bf16 hi/lo + fp32 bias + fp64 |c|^2 ----------------
__global__ __launch_bounds__(256) void vq_prep(const float* __restrict__ cb,
                                               unsigned short* __restrict__ cbh,
                                               unsigned short* __restrict__ cbl,
                                               float* __restrict__ bias,
                                               double* __restrict__ cc64) {
  int c = blockIdx.x * 256 + threadIdx.x;
  if (c >= Kc) return;
  const float4* row = (const float4*)(cb + (size_t)c * Dd);
  uint2* dh = (uint2*)(cbh + (size_t)c * Dd);
  uint2* dl = (uint2*)(cbl + (size_t)c * Dd);
  double s = 0.0;
  #pragma unroll 8
  for (int q = 0; q < 32; q++) {
    float4 v = row[q];
    s = fma((double)v.x, (double)v.x, s);
    s = fma((double)v.y, (double)v.y, s);
    s = fma((double)v.z, (double)v.z, s);
    s = fma((double)v.w, (double)v.w, s);
    unsigned h0 = f2bf(v.x), h1 = f2bf(v.y), h2 = f2bf(v.z), h3 = f2bf(v.w);
    unsigned l0 = f2bf(v.x - bf2f(h0)), l1 = f2bf(v.y - bf2f(h1));
    unsigned l2 = f2bf(v.z - bf2f(h2)), l3 = f2bf(v.w - bf2f(h3));
    uint2 ph; ph.x = h0 | (h1 << 16); ph.y = h2 | (h3 << 16);
    uint2 pl; pl.x = l0 | (l1 << 16); pl.y = l2 | (l3 << 16);
    dh[q] = ph; dl[q] = pl;
  }
  cc64[c] = s;
  bias[c] = (float)(-0.5 * s);
}

// ---------------- stage 1: split-bf16 MFMA scores + unpacked top-2 + margin ----------------
// 512 WGs x 256 thr; WG = 128 tokens; 8 chunks of 128 codes.
// MFMA 16x16x32: A = codes, B = tokens. C/D: col=lane&15, row=(lane>>4)*4+reg [m89].
__global__ __launch_bounds__(256) void vq_stage1(const float* __restrict__ z,
                                                 const float* __restrict__ cb,
                                                 const unsigned short* __restrict__ cbh,
                                                 const unsigned short* __restrict__ cbl,
                                                 const float* __restrict__ bias,
                                                 unsigned* __restrict__ counter,
                                                 unsigned* __restrict__ list,
                                                 float* __restrict__ out) {
  __shared__ uint4 zh4[2048];                // 32 KB [token][k] bf16 hi, XOR-swizzled
  __shared__ uint4 zl4[2048];                // 32 KB lo
  __shared__ uint4 ch4[2048];                // 32 KB [code][k] bf16 hi chunk
  __shared__ uint4 cl4[2048];                // 32 KB lo chunk
  __shared__ float4 res[128][8];             // 16 KB per-token (M1, M2, idx, -) x 8 slots
  __shared__ unsigned idxlds[128];
  __shared__ unsigned flg_list[128];
  __shared__ unsigned flg_n, flg_base;
  char* zh_lds = (char*)zh4; char* zl_lds = (char*)zl4;
  char* ch_lds = (char*)ch4; char* cl_lds = (char*)cl4;

  const int tid  = threadIdx.x;
  const int lane = tid & 63;
  const int wid  = tid >> 6;
  const int wm   = wid & 1;
  const int wn   = wid >> 1;
  const int lrow = lane >> 4;
  const int lcol = lane & 15;

  const int token0 = blockIdx.x * 128;
  const int b  = token0 >> 12;
  const int t0 = token0 & 4095;

  if (tid == 0) flg_n = 0;

  // ---- stage z tile (hi+lo), swizzled byte = (token*256 + d*2) ^ ((token&7)<<4)
  {
    const int token = tid & 127;
    const int dhalf = tid >> 7;
    const float* zb = z + (size_t)b * DT + (size_t)(t0 + token);
    #pragma unroll 4
    for (int i = 0; i < 32; i++) {
      int d = (i * 2 + dhalf) * 2;
      float f0 = zb[(size_t)d * Tt];
      float f1 = zb[(size_t)(d + 1) * Tt];
      unsigned h0 = f2bf(f0), h1 = f2bf(f1);
      unsigned l0 = f2bf(f0 - bf2f(h0)), l1 = f2bf(f1 - bf2f(h1));
      unsigned off = ((unsigned)(token * 256 + d * 2)) ^ (((unsigned)(token & 7)) << 4);
      *(unsigned*)(zh_lds + off) = h0 | (h1 << 16);
      *(unsigned*)(zl_lds + off) = l0 | (l1 << 16);
    }
  }

  float M1[4], M2[4];
  unsigned I1[4];
  #pragma unroll
  for (int nf = 0; nf < 4; nf++) { M1[nf] = NEG_INF; M2[nf] = NEG_INF; I1[nf] = 0; }

  #pragma unroll 1
  for (int cc = 0; cc < 8; cc++) {
    const int ccbase = cc * 128;
    __syncthreads();  // previous chunk's reads done before overwrite
    #pragma unroll
    for (int i = 0; i < 8; i++) {
      unsigned db  = (unsigned)(i * 4096 + wid * 1024 + lane * 16);
      unsigned row = db >> 8;
      unsigned kb  = db & 255u;
      unsigned goff = (((unsigned)ccbase + row) << 8) + (kb ^ ((row & 7u) << 4));
      ASYNC_COPY16(ch_lds + i * 4096 + wid * 1024, (const char*)cbh + goff);
      ASYNC_COPY16(cl_lds + i * 4096 + wid * 1024, (const char*)cbl + goff);
    }
    floatx4 acc[4][4];
    #pragma unroll
    for (int mf = 0; mf < 4; mf++) {
      floatx4 bv = *(const floatx4*)(bias + ccbase + wm * 64 + mf * 16 + lrow * 4);
      #pragma unroll
      for (int nf = 0; nf < 4; nf++) acc[mf][nf] = bv;
    }
    __syncthreads();  // staging drained (compiler emits vmcnt(0) before barrier)

    #pragma unroll
    for (int ks = 0; ks < 4; ks++) {
      shortx8 ah[4], al[4], bh[4], bl[4];
      const int kbyte = (ks * 32 + lrow * 8) * 2;
      #pragma unroll
      for (int mf = 0; mf < 4; mf++) {
        int row = wm * 64 + mf * 16 + lcol;
        unsigned off = ((unsigned)(row * 256 + kbyte)) ^ (((unsigned)(row & 7)) << 4);
        ah[mf] = *(const shortx8*)(ch_lds + off);
        al[mf] = *(const shortx8*)(cl_lds + off);
      }
      #pragma unroll
      for (int nf = 0; nf < 4; nf++) {
        int row = wn * 64 + nf * 16 + lcol;
        unsigned off = ((unsigned)(row * 256 + kbyte)) ^ (((unsigned)(row & 7)) << 4);
        bh[nf] = *(const shortx8*)(zh_lds + off);
        bl[nf] = *(const shortx8*)(zl_lds + off);
      }
      #pragma unroll
      for (int mf = 0; mf < 4; mf++)
        #pragma unroll
        for (int nf = 0; nf < 4; nf++) {
          acc[mf][nf] = __builtin_amdgcn_mfma_f32_16x16x32_bf16(ah[mf], bh[nf], acc[mf][nf], 0, 0, 0);
          acc[mf][nf] = __builtin_amdgcn_mfma_f32_16x16x32_bf16(al[mf], bh[nf], acc[mf][nf], 0, 0, 0);
          acc[mf][nf] = __builtin_amdgcn_mfma_f32_16x16x32_bf16(ah[mf], bl[nf], acc[mf][nf], 0, 0, 0);
        }
    }

    // epilogue: UNPACKED top-2 with index (no mantissa packing -> no quantization)
    #pragma unroll
    for (int mf = 0; mf < 4; mf++) {
      const unsigned ib = (unsigned)(ccbase + wm * 64 + mf * 16 + lrow * 4);
      #pragma unroll
      for (int j = 0; j < 4; j++) {
        const unsigned idx = ib + j;
        #pragma unroll
        for (int nf = 0; nf < 4; nf++) {
          float s = acc[mf][nf][j];
          bool gt = s > M1[nf];                      // strict: earlier (lower) idx wins ties
          M2[nf] = fmaxf(M2[nf], fminf(s, M1[nf]));
          I1[nf] = gt ? idx : I1[nf];
          M1[nf] = fmaxf(M1[nf], s);
        }
      }
    }
  }

  #pragma unroll
  for (int nf = 0; nf < 4; nf++) {
    int token = wn * 64 + nf * 16 + lcol;
    res[token][wm * 4 + lrow] = make_float4(M1[nf], M2[nf], __uint_as_float(I1[nf]), 0.f);
  }
  __syncthreads();

  if (tid < 128) {
    float g1 = NEG_INF, g2 = NEG_INF; unsigned gi = 0;
    #pragma unroll
    for (int s = 0; s < 8; s++) {
      float4 v = res[tid][s];
      bool better = v.x > g1;
      float loser = better ? g1 : v.x;               // min(v.x, g1)
      g2 = fmaxf(g2, fmaxf(loser, v.y));
      gi = better ? __float_as_uint(v.z) : gi;
      g1 = fmaxf(g1, v.x);
    }
    idxlds[tid] = gi;
    if (g1 - g2 < DELTA) {
      unsigned p = atomicAdd(&flg_n, 1u);            // LDS atomic, cheap
      flg_list[p] = (unsigned)(token0 + tid);
    }
  }
  __syncthreads();
  if (tid == 0 && flg_n > 0) flg_base = atomicAdd(counter, flg_n);   // ONE global atomic/WG
  __syncthreads();
  if (tid < flg_n) list[flg_base + tid] = flg_list[tid];

  // gather + scatter-write candidate rows (flagged tokens overwritten by rescue)
  {
    const int token = tid & 127;
    const int half  = tid >> 7;
    const unsigned idx = idxlds[token];
    const float4* crow = (const float4*)(cb + (size_t)idx * Dd);
    const size_t obase = (size_t)b * DT + (size_t)(t0 + token);
    #pragma unroll
    for (int q = 0; q < 16; q++) {
      int d = half * 64 + q * 4;
      float4 v = crow[d >> 2];
      out[obase + (size_t)(d + 0) * Tt] = v.x;
      out[obase + (size_t)(d + 1) * Tt] = v.y;
      out[obase + (size_t)(d + 2) * Tt] = v.z;
      out[obase + (size_t)(d + 3) * Tt] = v.w;
    }
  }
}

// ---------------- rescue: EXACT fp64 re-scan for flagged tokens ----------------
__global__ __launch_bounds__(256) void vq_rescue(const float* __restrict__ z,
                                                 const float* __restrict__ cb,
                                                 const double* __restrict__ cc64,
                                                 const unsigned* __restrict__ counter,
                                                 const unsigned* __restrict__ list,
                                                 float* __restrict__ out) {
  const int tid = threadIdx.x;
  const unsigned count = *counter;
  __shared__ float zbuf[8][128];
  __shared__ double zz[8];
  __shared__ double rv[4][8];
  __shared__ int    rc[4][8];
  __shared__ int    fidx[8];
  __shared__ unsigned toks[8];

  for (unsigned base = blockIdx.x * 8u; base < count; base += gridDim.x * 8u) {
    unsigned rem = count - base;
    int nt = rem < 8u ? (int)rem : 8;
    __syncthreads();
    if (tid < nt) toks[tid] = list[base + tid];
    __syncthreads();
    for (int e = tid; e < nt * 128; e += 256) {
      int j = e >> 7, d = e & 127;
      unsigned tk = toks[j];
      zbuf[j][d] = z[(size_t)(tk >> 12) * DT + (size_t)d * Tt + (tk & 4095u)];
    }
    __syncthreads();
    if (tid < 8) {
      double s = 0.0;
      #pragma unroll 16
      for (int d = 0; d < 128; d++) {
        double v = (double)zbuf[tid][d];
        s = fma(v, v, s);
      }
      zz[tid] = s;
    }

    double acc[8][4];
    #pragma unroll
    for (int j = 0; j < 8; j++)
      #pragma unroll
      for (int q = 0; q < 4; q++) acc[j][q] = 0.0;

    for (int d0 = 0; d0 < 128; d0 += 4) {
      double cvd[4][4];
      #pragma unroll
      for (int q = 0; q < 4; q++) {
        float4 cv = *(const float4*)(cb + (size_t)(q * 256 + tid) * Dd + d0);
        cvd[q][0] = (double)cv.x; cvd[q][1] = (double)cv.y;
        cvd[q][2] = (double)cv.z; cvd[q][3] = (double)cv.w;
      }
      #pragma unroll
      for (int j = 0; j < 8; j++) {
        float4 zv = *(const float4*)&zbuf[j][d0];
        double z0 = (double)zv.x, z1 = (double)zv.y, z2 = (double)zv.z, z3 = (double)zv.w;
        #pragma unroll
        for (int q = 0; q < 4; q++)
          acc[j][q] = fma(z0, cvd[q][0], fma(z1, cvd[q][1], fma(z2, cvd[q][2], fma(z3, cvd[q][3], acc[j][q]))));
      }
    }
    __syncthreads();

    #pragma unroll
    for (int j = 0; j < 8; j++) {
      double bv = __builtin_inf(); int bc = 0x7fffffff;
      double zzj = zz[j];
      #pragma unroll
      for (int q = 0; q < 4; q++) {
        int c = q * 256 + tid;
        double d2 = zzj - 2.0 * acc[j][q] + cc64[c];
        if (d2 < bv || (d2 == bv && c < bc)) { bv = d2; bc = c; }
      }
      #pragma unroll
      for (int off = 32; off > 0; off >>= 1) {
        double ov = __shfl_xor(bv, off);
        int    oc = __shfl_xor(bc, off);
        if (ov < bv || (ov == bv && oc < bc)) { bv = ov; bc = oc; }
      }
      if ((tid & 63) == 0) { rv[tid >> 6][j] = bv; rc[tid >> 6][j] = bc; }
    }
    __syncthreads();
    if (tid < 8) {
      int j = tid; double bv = rv[0][j]; int bc = rc[0][j];
      #pragma unroll
      for (int w = 1; w < 4; w++) {
        double ov = rv[w][j]; int oc = rc[w][j];
        if (ov < bv || (ov == bv && oc < bc)) { bv = ov; bc = oc; }
      }
      fidx[j] = bc;
    }
    __syncthreads();
    for (int j = 0; j < nt; j++) {
      unsigned tk = toks[j];
      int c = fidx[j];
      for (int d = tid; d < 128; d += 256)
        out[(size_t)(tk >> 12) * DT + (size_t)d * Tt + (tk & 4095u)] = cb[(size_t)c * Dd + d];
    }
  }
}

extern "C" void kernel_launch(void* const* d_in, const int* in_sizes, int n_in,
                              void* d_out, int out_size, void* d_ws, size_t ws_size,
                              hipStream_t stream) {
  const float* z  = (const float*)d_in[0];
  const float* cb = (const float*)d_in[1];
  float* out = (float*)d_out;

  // ws layout (800 KB):
  //   counter u32 @0 | bias f32[1024] @4K | cc64 f64[1024] @16K |
  //   cbh bf16[131072] @32K (256KB) | cbl @288K (256KB) | list u32[65536] @544K (256KB)
  char* ws = (char*)d_ws;
  unsigned*       counter = (unsigned*)ws;
  float*          bias    = (float*)(ws + (4u << 10));
  double*         cc64    = (double*)(ws + (16u << 10));
  unsigned short* cbh     = (unsigned short*)(ws + (32u << 10));
  unsigned short* cbl     = (unsigned short*)(ws + (288u << 10));
  unsigned*       list    = (unsigned*)(ws + (544u << 10));

  hipMemsetAsync(d_ws, 0, 4, stream);
  hipLaunchKernelGGL(vq_prep,   dim3(4),   dim3(256), 0, stream, cb, cbh, cbl, bias, cc64);
  hipLaunchKernelGGL(vq_stage1, dim3(512), dim3(256), 0, stream, z, cb, cbh, cbl, bias, counter, list, out);
  hipLaunchKernelGGL(vq_rescue, dim3(512), dim3(256), 0, stream, z, cb, cc64, counter, list, out);
}

// Round 8
// 204.943 us; speedup vs baseline: 1.1801x; 1.0181x over previous
//
#include <hip/hip_runtime.h>

// z [B=16, D=128, T=4096] fp32, codebook [K=1024, D=128] fp32.
// out = codebook[argmin_k ||z_tok - c_k||^2] scattered back to [B, D, T].
// Stage 1: argmax s, s = z.c - 0.5|c|^2 via bf16-SPLIT MFMA (zh.ch + zl.ch + zh.cl),
//   residual error sigma ~1.5e-4 (MFMA fp32 accum) + 4.6e-5 (dropped zl.cl).
// Per-token top-2 via per-lane scan + idx-aware shfl_xor merge (duplicate-proof)
//   + disjoint-half LDS merge. margin < DELTA=0.005 (~30 sigma) -> fp64 rescue.
// Rescue: 8-token batched exact fp64 (benched r5: passed; robust at any count).
// r7 audit: r4 count == 32768 exactly (half) => deterministic merge-duplication
// signature; this kernel's merge is duplicate-proof by construction.

#define Dd 128
#define Tt 4096
#define Kc 1024
#define DT (Dd*Tt)
#define DELTA 0.005f
#define NEG_INF (-__builtin_inff())

typedef float  floatx4 __attribute__((ext_vector_type(4)));
typedef short  shortx8 __attribute__((ext_vector_type(8)));

__device__ __forceinline__ unsigned f2bf(float f) {
  unsigned u = __float_as_uint(f);
  u = u + 0x7fffu + ((u >> 16) & 1u);   // RNE to bf16
  return u >> 16;
}
__device__ __forceinline__ float bf2f(unsigned h) { return __uint_as_float(h << 16); }

#define ASYNC_COPY16(dst, src) \
  __builtin_amdgcn_global_load_lds((const __attribute__((address_space(1))) void*)(src), \
                                   (__attribute__((address_space(3))) void*)(dst), 16, 0, 0)

// ---------------- prep: codebook -> bf16 hi/lo + fp32 bias + fp64 |c|^2 ----------------
__global__ __launch_bounds__(256) void vq_prep(const float* __restrict__ cb,
                                               unsigned short* __restrict__ cbh,
                                               unsigned short* __restrict__ cbl,
                                               float* __restrict__ bias,
                                               double* __restrict__ cc64) {
  int c = blockIdx.x * 256 + threadIdx.x;
  if (c >= Kc) return;
  const float4* row = (const float4*)(cb + (size_t)c * Dd);
  uint2* dh = (uint2*)(cbh + (size_t)c * Dd);
  uint2* dl = (uint2*)(cbl + (size_t)c * Dd);
  double s = 0.0;
  #pragma unroll 8
  for (int q = 0; q < 32; q++) {
    float4 v = row[q];
    s = fma((double)v.x, (double)v.x, s);
    s = fma((double)v.y, (double)v.y, s);
    s = fma((double)v.z, (double)v.z, s);
    s = fma((double)v.w, (double)v.w, s);
    unsigned h0 = f2bf(v.x), h1 = f2bf(v.y), h2 = f2bf(v.z), h3 = f2bf(v.w);
    unsigned l0 = f2bf(v.x - bf2f(h0)), l1 = f2bf(v.y - bf2f(h1));
    unsigned l2 = f2bf(v.z - bf2f(h2)), l3 = f2bf(v.w - bf2f(h3));
    uint2 ph; ph.x = h0 | (h1 << 16); ph.y = h2 | (h3 << 16);
    uint2 pl; pl.x = l0 | (l1 << 16); pl.y = l2 | (l3 << 16);
    dh[q] = ph; dl[q] = pl;
  }
  cc64[c] = s;
  bias[c] = (float)(-0.5 * s);
}

// ---------------- stage 1 ----------------
// 512 WGs x 256 thr; WG = 128 tokens; 8 chunks of 128 codes.
// MFMA 16x16x32: A = codes, B = tokens. C/D: col=lane&15, row=(lane>>4)*4+reg [m89].
// XOR swizzle: byte = (row*256 + kb) ^ ((row&15)<<4) — bijective in-row, same
// formula on write and read (both-sides rule); reads 2-way (free), writes 4-way.
__global__ __launch_bounds__(256) void vq_stage1(const float* __restrict__ z,
                                                 const float* __restrict__ cb,
                                                 const unsigned short* __restrict__ cbh,
                                                 const unsigned short* __restrict__ cbl,
                                                 const float* __restrict__ bias,
                                                 unsigned* __restrict__ counter,
                                                 unsigned* __restrict__ list,
                                                 float* __restrict__ out) {
  __shared__ uint4 zh4[2048];                // 32 KB [token][k] bf16 hi, XOR-swizzled
  __shared__ uint4 zl4[2048];                // 32 KB lo
  __shared__ uint4 ch4[2048];                // 32 KB [code][k] bf16 hi chunk
  __shared__ uint4 cl4[2048];                // 32 KB lo chunk
  __shared__ float mbuf[2][128][3];          // 3 KB  [wm][token][{M1,M2,I1bits}]
  __shared__ unsigned idxlds[128];
  __shared__ unsigned flg_list[128];
  __shared__ unsigned flg_n, flg_base;
  char* zh_lds = (char*)zh4; char* zl_lds = (char*)zl4;
  char* ch_lds = (char*)ch4; char* cl_lds = (char*)cl4;

  const int tid  = threadIdx.x;
  const int lane = tid & 63;
  const int wid  = tid >> 6;
  const int wm   = wid & 1;
  const int wn   = wid >> 1;
  const int lrow = lane >> 4;
  const int lcol = lane & 15;

  const int token0 = blockIdx.x * 128;
  const int b  = token0 >> 12;
  const int t0 = token0 & 4095;

  if (tid == 0) flg_n = 0;

  // ---- stage z tile (hi+lo) via register-packed ds_write_b128
  {
    const int token = tid & 127;
    const int dhalf = tid >> 7;
    const float* zb = z + (size_t)b * DT + (size_t)(t0 + token);
    #pragma unroll
    for (int blk = 0; blk < 8; blk++) {
      const int d0 = dhalf * 64 + blk * 8;
      unsigned hi[4], lo[4];
      #pragma unroll
      for (int k2 = 0; k2 < 4; k2++) {
        float f0 = zb[(size_t)(d0 + 2 * k2) * Tt];
        float f1 = zb[(size_t)(d0 + 2 * k2 + 1) * Tt];
        unsigned h0 = f2bf(f0), h1 = f2bf(f1);
        hi[k2] = h0 | (h1 << 16);
        lo[k2] = f2bf(f0 - bf2f(h0)) | (f2bf(f1 - bf2f(h1)) << 16);
      }
      unsigned off = ((unsigned)(token * 256 + d0 * 2)) ^ (((unsigned)(token & 15)) << 4);
      uint4 vh; vh.x = hi[0]; vh.y = hi[1]; vh.z = hi[2]; vh.w = hi[3];
      uint4 vl; vl.x = lo[0]; vl.y = lo[1]; vl.z = lo[2]; vl.w = lo[3];
      *(uint4*)(zh_lds + off) = vh;
      *(uint4*)(zl_lds + off) = vl;
    }
  }

  float M1[4], M2[4];
  unsigned I1[4];
  #pragma unroll
  for (int nf = 0; nf < 4; nf++) { M1[nf] = NEG_INF; M2[nf] = NEG_INF; I1[nf] = 0; }

  #pragma unroll 1
  for (int cc = 0; cc < 8; cc++) {
    const int ccbase = cc * 128;
    __syncthreads();  // previous chunk's reads done before overwrite
    #pragma unroll
    for (int i = 0; i < 8; i++) {
      unsigned db  = (unsigned)(i * 4096 + wid * 1024 + lane * 16);
      unsigned row = db >> 8;
      unsigned kb  = db & 255u;
      unsigned goff = (((unsigned)ccbase + row) << 8) + (kb ^ ((row & 15u) << 4));
      ASYNC_COPY16(ch_lds + i * 4096 + wid * 1024, (const char*)cbh + goff);
      ASYNC_COPY16(cl_lds + i * 4096 + wid * 1024, (const char*)cbl + goff);
    }
    floatx4 acc[4][4];
    #pragma unroll
    for (int mf = 0; mf < 4; mf++) {
      floatx4 bv = *(const floatx4*)(bias + ccbase + wm * 64 + mf * 16 + lrow * 4);
      #pragma unroll
      for (int nf = 0; nf < 4; nf++) acc[mf][nf] = bv;
    }
    __syncthreads();  // staging drained (compiler emits vmcnt(0) before barrier)

    #pragma unroll
    for (int ks = 0; ks < 4; ks++) {
      shortx8 ah[4], al[4], bh[4], bl[4];
      const int kbyte = (ks * 32 + lrow * 8) * 2;
      #pragma unroll
      for (int mf = 0; mf < 4; mf++) {
        int row = wm * 64 + mf * 16 + lcol;
        unsigned off = ((unsigned)(row * 256 + kbyte)) ^ (((unsigned)(row & 15)) << 4);
        ah[mf] = *(const shortx8*)(ch_lds + off);
        al[mf] = *(const shortx8*)(cl_lds + off);
      }
      #pragma unroll
      for (int nf = 0; nf < 4; nf++) {
        int row = wn * 64 + nf * 16 + lcol;
        unsigned off = ((unsigned)(row * 256 + kbyte)) ^ (((unsigned)(row & 15)) << 4);
        bh[nf] = *(const shortx8*)(zh_lds + off);
        bl[nf] = *(const shortx8*)(zl_lds + off);
      }
      #pragma unroll
      for (int mf = 0; mf < 4; mf++)
        #pragma unroll
        for (int nf = 0; nf < 4; nf++) {
          acc[mf][nf] = __builtin_amdgcn_mfma_f32_16x16x32_bf16(ah[mf], bh[nf], acc[mf][nf], 0, 0, 0);
          acc[mf][nf] = __builtin_amdgcn_mfma_f32_16x16x32_bf16(al[mf], bh[nf], acc[mf][nf], 0, 0, 0);
          acc[mf][nf] = __builtin_amdgcn_mfma_f32_16x16x32_bf16(ah[mf], bl[nf], acc[mf][nf], 0, 0, 0);
        }
    }

    // per-lane top-2 (each code presented exactly once per lane)
    #pragma unroll
    for (int mf = 0; mf < 4; mf++) {
      const unsigned ib = (unsigned)(ccbase + wm * 64 + mf * 16 + lrow * 4);
      #pragma unroll
      for (int j = 0; j < 4; j++) {
        const unsigned idx = ib + j;
        #pragma unroll
        for (int nf = 0; nf < 4; nf++) {
          float s = acc[mf][nf][j];
          bool gt = s > M1[nf];
          M2[nf] = fmaxf(M2[nf], fminf(s, M1[nf]));
          I1[nf] = gt ? idx : I1[nf];
          M1[nf] = fmaxf(M1[nf], s);
        }
      }
    }
  }

  // ---- in-wave idx-aware top-2 merge across the 4 lrow groups (lanes ^16, ^32)
  // lrow groups hold DISJOINT code subsets; duplicate-of-best candidates are
  // absorbed into M1 and can never pollute M2.
  #pragma unroll
  for (int dmask = 16; dmask < 64; dmask <<= 1) {
    #pragma unroll
    for (int nf = 0; nf < 4; nf++) {
      float m1 = __shfl_xor(M1[nf], dmask);
      float m2 = __shfl_xor(M2[nf], dmask);
      unsigned i1 = (unsigned)__shfl_xor((int)I1[nf], dmask);
      if (i1 == I1[nf]) {            // duplicate of current best: absorb
        M1[nf] = fmaxf(M1[nf], m1);
        M2[nf] = fmaxf(M2[nf], m2);
      } else {
        bool win = m1 > M1[nf];
        float lose = win ? M1[nf] : m1;
        I1[nf] = win ? i1 : I1[nf];
        M1[nf] = fmaxf(M1[nf], m1);
        M2[nf] = fmaxf(M2[nf], fmaxf(m2, lose));
      }
    }
  }
  // lanes 0..15 of each wave publish per-(wm,token) results; codes disjoint across wm
  if (lrow == 0) {
    #pragma unroll
    for (int nf = 0; nf < 4; nf++) {
      int token = wn * 64 + nf * 16 + lcol;
      mbuf[wm][token][0] = M1[nf];
      mbuf[wm][token][1] = M2[nf];
      mbuf[wm][token][2] = __uint_as_float(I1[nf]);
    }
  }
  __syncthreads();

  if (tid < 128) {
    float a1 = mbuf[0][tid][0], a2 = mbuf[0][tid][1];
    unsigned ai = __float_as_uint(mbuf[0][tid][2]);
    float b1 = mbuf[1][tid][0], b2 = mbuf[1][tid][1];
    unsigned bi = __float_as_uint(mbuf[1][tid][2]);
    bool win = b1 > a1;                       // strict: tie keeps wm=0 (lower idx)
    float g1 = fmaxf(a1, b1);
    unsigned gi = win ? bi : ai;
    float g2 = fmaxf(fmaxf(a2, b2), fminf(a1, b1));
    idxlds[tid] = gi;
    if (g1 - g2 < DELTA) {
      unsigned p = atomicAdd(&flg_n, 1u);
      flg_list[p] = (unsigned)(token0 + tid);
    }
  }
  __syncthreads();
  if (tid == 0 && flg_n > 0) flg_base = atomicAdd(counter, flg_n);
  __syncthreads();
  if (tid < flg_n) list[flg_base + tid] = flg_list[tid];

  // gather + scatter-write candidate rows (flagged tokens overwritten by rescue)
  {
    const int token = tid & 127;
    const int half  = tid >> 7;
    const unsigned idx = idxlds[token];
    const float4* crow = (const float4*)(cb + (size_t)idx * Dd);
    const size_t obase = (size_t)b * DT + (size_t)(t0 + token);
    #pragma unroll
    for (int q = 0; q < 16; q++) {
      int d = half * 64 + q * 4;
      float4 v = crow[d >> 2];
      out[obase + (size_t)(d + 0) * Tt] = v.x;
      out[obase + (size_t)(d + 1) * Tt] = v.y;
      out[obase + (size_t)(d + 2) * Tt] = v.z;
      out[obase + (size_t)(d + 3) * Tt] = v.w;
    }
  }
}

// ---------------- rescue: EXACT fp64 re-scan, 8 tokens per WG-iteration ----------------
// (benched r5: passed. Amortizes codebook reads; robust at any flag count.)
__global__ __launch_bounds__(256) void vq_rescue(const float* __restrict__ z,
                                                 const float* __restrict__ cb,
                                                 const double* __restrict__ cc64,
                                                 const unsigned* __restrict__ counter,
                                                 const unsigned* __restrict__ list,
                                                 float* __restrict__ out) {
  const int tid = threadIdx.x;
  const unsigned count = *counter;
  __shared__ float zbuf[8][128];
  __shared__ double zz[8];
  __shared__ double rv[4][8];
  __shared__ int    rc[4][8];
  __shared__ int    fidx[8];
  __shared__ unsigned toks[8];

  for (unsigned base = blockIdx.x * 8u; base < count; base += gridDim.x * 8u) {
    unsigned rem = count - base;
    int nt = rem < 8u ? (int)rem : 8;
    __syncthreads();
    if (tid < nt) toks[tid] = list[base + tid];
    __syncthreads();
    for (int e = tid; e < nt * 128; e += 256) {
      int j = e >> 7, d = e & 127;
      unsigned tk = toks[j];
      zbuf[j][d] = z[(size_t)(tk >> 12) * DT + (size_t)d * Tt + (tk & 4095u)];
    }
    __syncthreads();
    if (tid < 8) {
      double s = 0.0;
      #pragma unroll 16
      for (int d = 0; d < 128; d++) {
        double v = (double)zbuf[tid][d];
        s = fma(v, v, s);
      }
      zz[tid] = s;
    }

    double acc[8][4];
    #pragma unroll
    for (int j = 0; j < 8; j++)
      #pragma unroll
      for (int q = 0; q < 4; q++) acc[j][q] = 0.0;

    for (int d0 = 0; d0 < 128; d0 += 4) {
      double cvd[4][4];
      #pragma unroll
      for (int q = 0; q < 4; q++) {
        float4 cv = *(const float4*)(cb + (size_t)(q * 256 + tid) * Dd + d0);
        cvd[q][0] = (double)cv.x; cvd[q][1] = (double)cv.y;
        cvd[q][2] = (double)cv.z; cvd[q][3] = (double)cv.w;
      }
      #pragma unroll
      for (int j = 0; j < 8; j++) {
        float4 zv = *(const float4*)&zbuf[j][d0];
        double z0 = (double)zv.x, z1 = (double)zv.y, z2 = (double)zv.z, z3 = (double)zv.w;
        #pragma unroll
        for (int q = 0; q < 4; q++)
          acc[j][q] = fma(z0, cvd[q][0], fma(z1, cvd[q][1], fma(z2, cvd[q][2], fma(z3, cvd[q][3], acc[j][q]))));
      }
    }
    __syncthreads();

    #pragma unroll
    for (int j = 0; j < 8; j++) {
      double bv = __builtin_inf(); int bc = 0x7fffffff;
      double zzj = zz[j];
      #pragma unroll
      for (int q = 0; q < 4; q++) {
        int c = q * 256 + tid;
        double d2 = zzj - 2.0 * acc[j][q] + cc64[c];
        if (d2 < bv || (d2 == bv && c < bc)) { bv = d2; bc = c; }
      }
      #pragma unroll
      for (int off = 32; off > 0; off >>= 1) {
        double ov = __shfl_xor(bv, off);
        int    oc = __shfl_xor(bc, off);
        if (ov < bv || (ov == bv && oc < bc)) { bv = ov; bc = oc; }
      }
      if ((tid & 63) == 0) { rv[tid >> 6][j] = bv; rc[tid >> 6][j] = bc; }
    }
    __syncthreads();
    if (tid < 8) {
      int j = tid; double bv = rv[0][j]; int bc = rc[0][j];
      #pragma unroll
      for (int w = 1; w < 4; w++) {
        double ov = rv[w][j]; int oc = rc[w][j];
        if (ov < bv || (ov == bv && oc < bc)) { bv = ov; bc = oc; }
      }
      fidx[j] = bc;
    }
    __syncthreads();
    for (int j = 0; j < nt; j++) {
      unsigned tk = toks[j];
      int c = fidx[j];
      for (int d = tid; d < 128; d += 256)
        out[(size_t)(tk >> 12) * DT + (size_t)d * Tt + (tk & 4095u)] = cb[(size_t)c * Dd + d];
    }
  }
}

extern "C" void kernel_launch(void* const* d_in, const int* in_sizes, int n_in,
                              void* d_out, int out_size, void* d_ws, size_t ws_size,
                              hipStream_t stream) {
  const float* z  = (const float*)d_in[0];
  const float* cb = (const float*)d_in[1];
  float* out = (float*)d_out;

  // ws layout (800 KB):
  //   counter u32 @0 | bias f32[1024] @4K | cc64 f64[1024] @16K |
  //   cbh bf16[131072] @32K (256KB) | cbl @288K (256KB) | list u32[65536] @544K (256KB)
  char* ws = (char*)d_ws;
  unsigned*       counter = (unsigned*)ws;
  float*          bias    = (float*)(ws + (4u << 10));
  double*         cc64    = (double*)(ws + (16u << 10));
  unsigned short* cbh     = (unsigned short*)(ws + (32u << 10));
  unsigned short* cbl     = (unsigned short*)(ws + (288u << 10));
  unsigned*       list    = (unsigned*)(ws + (544u << 10));

  hipMemsetAsync(d_ws, 0, 4, stream);
  hipLaunchKernelGGL(vq_prep,   dim3(4),   dim3(256), 0, stream, cb, cbh, cbl, bias, cc64);
  hipLaunchKernelGGL(vq_stage1, dim3(512), dim3(256), 0, stream, z, cb, cbh, cbl, bias, counter, list, out);
  hipLaunchKernelGGL(vq_rescue, dim3(512), dim3(256), 0, stream, z, cb, cc64, counter, list, out);
}